// Round 5
// baseline (2574.463 us; speedup 1.0000x reference)
//
#include <hip/hip_runtime.h>
#include <math.h>

#define BATCH     512
#define T_PAST_   360
#define T_FUT_    1800
#define IN_SZ     3
#define H_SZ      64
#define FUT_SEQ   50
#define WSPF_     34
#define MAX_STEPS (FUT_SEQ * WSPF_)      // 1700
#define T_TOT     (T_PAST_ + MAX_STEPS)  // 2060

__device__ __forceinline__ float rcp_(float x) {
    return __builtin_amdgcn_rcpf(x);     // v_rcp_f32
}

__device__ __forceinline__ float sigmoid_(float x) {
    return rcp_(1.0f + __expf(-x));
}

__device__ __forceinline__ float tanh_(float x) {
    float a = fabsf(x);
    float e = __expf(-2.0f * a);         // in (0,1], no overflow
    float t = (1.0f - e) * rcp_(1.0f + e);
    return copysignf(t, x);
}

// wave-wide broadcast of lane `src`'s value (SGPR operand into consumer)
__device__ __forceinline__ float bcast_(float v, int src) {
    return __int_as_float(__builtin_amdgcn_readlane(__float_as_int(v), src));
}

// 2 waves per batch element, K-split LSTM.
// Lane l (in BOTH waves) owns hidden unit l: after the per-step partial-sum
// exchange it holds all 4 gate pre-activations of unit l, does activations and
// the c/h update fully in registers (redundantly in each wave). Wave w holds
// W_hh[g*64+l][k] for k in [32w,32w+32) -> 128 weight VGPRs (fits in v0..v255;
// the round-4 one-wave variant needed ~290 live regs and spilled to scratch).
__global__ __launch_bounds__(128, 1)
void lstm_fused_kernel(const float* __restrict__ wave_input,   // [B, 360, 3]
                       const float* __restrict__ wave_future,  // [B, 1800, 3]
                       const float* __restrict__ W_ih,         // [256, 3]
                       const float* __restrict__ W_hh,         // [256, 64]
                       const float* __restrict__ b_ih,         // [256]
                       const float* __restrict__ b_hh,         // [256]
                       const float* __restrict__ W_proj,       // [64, 64]
                       const float* __restrict__ b_proj,       // [64]
                       float* __restrict__ out)                // [B, 50, 64]
{
    __shared__ __align__(16) float x_lds[T_TOT * IN_SZ];     // 24.7 KB
    __shared__ __align__(16) float wproj_lds[H_SZ * 65];     // 16.6 KB, padded
    __shared__ __align__(16) float prt[2][2][4][H_SZ];       // [t&1][wv][gate][unit] 4 KB

    const int b    = blockIdx.x;
    const int tid  = threadIdx.x;
    const int wv   = tid >> 6;          // 0 or 1
    const int lane = tid & 63;          // hidden unit index

    // ---- stage x sequence (coalesced) ----
    {
        const float* wi = wave_input + (size_t)b * (T_PAST_ * IN_SZ);
        for (int i = tid; i < T_PAST_ * IN_SZ; i += 128) x_lds[i] = wi[i];
        const float* wf = wave_future + (size_t)b * (T_FUT_ * IN_SZ);
        for (int i = tid; i < MAX_STEPS * IN_SZ; i += 128)
            x_lds[T_PAST_ * IN_SZ + i] = wf[i];
    }
    // ---- W_proj rows, stride-65 padding (2 lanes/bank on reads = free) ----
    for (int i = tid; i < H_SZ * H_SZ; i += 128) {
        int r = i >> 6, cc = i & 63;
        wproj_lds[r * 65 + cc] = W_proj[i];
    }

    // ---- this wave's K-half of the 4 gate rows for unit `lane` ----
    float wk[4][32];
    #pragma unroll
    for (int g = 0; g < 4; ++g) {
        const float4* p = (const float4*)(W_hh + (size_t)(g * H_SZ + lane) * H_SZ + wv * 32);
        #pragma unroll
        for (int q = 0; q < 8; ++q) {
            float4 v = p[q];
            wk[g][4*q+0] = v.x; wk[g][4*q+1] = v.y;
            wk[g][4*q+2] = v.z; wk[g][4*q+3] = v.w;
        }
    }
    // ---- preamble (bias + W_ih·x) split: wave w covers gates 2w, 2w+1 ----
    const int gA = 2 * wv * H_SZ + lane;          // gate 2w, unit lane
    const int gBr = (2 * wv + 1) * H_SZ + lane;   // gate 2w+1
    const float wA0 = W_ih[gA*3+0],  wA1 = W_ih[gA*3+1],  wA2 = W_ih[gA*3+2];
    const float wB0 = W_ih[gBr*3+0], wB1 = W_ih[gBr*3+1], wB2 = W_ih[gBr*3+2];
    const float bA = b_ih[gA]  + b_hh[gA];
    const float bB = b_ih[gBr] + b_hh[gBr];
    const float bpj = b_proj[lane];

    float h = 0.0f, c = 0.0f;           // unit `lane` state (copy per wave)
    float* outb = out + (size_t)b * (FUT_SEQ * H_SZ);
    int next_cp = T_PAST_ + WSPF_ - 1;
    int cp_k = 0;

    __syncthreads();

    for (int t = 0; t < T_TOT; ++t) {
        float x0 = x_lds[t * 3 + 0];    // uniform-address broadcast reads
        float x1 = x_lds[t * 3 + 1];
        float x2 = x_lds[t * 3 + 2];

        float pA = fmaf(wA0, x0, fmaf(wA1, x1, fmaf(wA2, x2, bA)));
        float pB = fmaf(wB0, x0, fmaf(wB1, x1, fmaf(wB2, x2, bB)));
        float a0, a1, a2, a3;
        if (wv == 0) { a0 = pA; a1 = pB; a2 = 0.0f; a3 = 0.0f; }
        else         { a0 = 0.0f; a1 = 0.0f; a2 = pA; a3 = pB; }

        // ---- partial dot over own K-half; h broadcast via readlane ----
        #pragma unroll
        for (int k = 0; k < 32; ++k) {
            float hk = bcast_(h, wv * 32 + k);
            a0 = fmaf(wk[0][k], hk, a0);
            a1 = fmaf(wk[1][k], hk, a1);
            a2 = fmaf(wk[2][k], hk, a2);
            a3 = fmaf(wk[3][k], hk, a3);
        }

        // ---- exchange partials (double-buffered, one barrier per step) ----
        float* mine = &prt[t & 1][wv][0][lane];
        mine[0 * H_SZ] = a0; mine[1 * H_SZ] = a1;
        mine[2 * H_SZ] = a2; mine[3 * H_SZ] = a3;
        __syncthreads();
        const float* oth = &prt[t & 1][1 - wv][0][lane];
        float s0 = a0 + oth[0 * H_SZ];
        float s1 = a1 + oth[1 * H_SZ];
        float s2 = a2 + oth[2 * H_SZ];
        float s3 = a3 + oth[3 * H_SZ];

        // ---- activations + state update, in-lane (both waves redundant) ----
        float gi = sigmoid_(s0);
        float gf = sigmoid_(s1);
        float gg = tanh_(s2);
        float go = sigmoid_(s3);
        c = fmaf(gf, c, gi * gg);
        h = go * tanh_(c);

        if (t == next_cp) {             // block-uniform
            float p = bpj;
            #pragma unroll 8
            for (int m = 0; m < H_SZ; ++m)
                p = fmaf(wproj_lds[lane * 65 + m], bcast_(h, m), p);
            if (wv == 0) outb[cp_k * H_SZ + lane] = p;
            next_cp += WSPF_;
            ++cp_k;
        }
    }
}

extern "C" void kernel_launch(void* const* d_in, const int* in_sizes, int n_in,
                              void* d_out, int out_size, void* d_ws, size_t ws_size,
                              hipStream_t stream) {
    const float* wave_input  = (const float*)d_in[0];
    const float* wave_future = (const float*)d_in[1];
    const float* W_ih        = (const float*)d_in[2];
    const float* W_hh        = (const float*)d_in[3];
    const float* b_ih        = (const float*)d_in[4];
    const float* b_hh        = (const float*)d_in[5];
    const float* W_proj      = (const float*)d_in[6];
    const float* b_proj      = (const float*)d_in[7];
    float* out               = (float*)d_out;

    lstm_fused_kernel<<<BATCH, 128, 0, stream>>>(
        wave_input, wave_future, W_ih, W_hh, b_ih, b_hh, W_proj, b_proj, out);
}

// Round 6
// 1272.269 us; speedup vs baseline: 2.0235x; 2.0235x over previous
//
#include <hip/hip_runtime.h>
#include <math.h>

#define BATCH     512
#define T_PAST_   360
#define T_FUT_    1800
#define IN_SZ     3
#define H_SZ      64
#define FUT_SEQ   50
#define WSPF_     34
#define MAX_STEPS (FUT_SEQ * WSPF_)      // 1700
#define T_TOT     (T_PAST_ + MAX_STEPS)  // 2060
#define NTHREADS  256

__device__ __forceinline__ float rcp_(float x) {
    return __builtin_amdgcn_rcpf(x);     // v_rcp_f32
}

__device__ __forceinline__ float tanh_(float x) {
    float a = fabsf(x);
    float e = __expf(-2.0f * a);         // in (0,1], no overflow
    float t = (1.0f - e) * rcp_(1.0f + e);
    return copysignf(t, x);
}

// wave-wide broadcast of lane `src`'s value (v_readlane -> SGPR operand)
__device__ __forceinline__ float bcast_(float v, int src) {
    return __int_as_float(__builtin_amdgcn_readlane(__float_as_int(v), src));
}

// Thread = gate row (256 threads, 4 waves, 1 batch element per block).
// Every wave redundantly maintains h[lane], c[lane] in registers, so the
// h-broadcast for the W_hh dot is an in-wave v_readlane (no LDS, no extra
// barrier). The 64 W_hh weights per thread are loaded ONCE and pinned into
// VGPRs with an asm barrier so the compiler cannot sink the loads into the
// time loop (the silent failure of rounds 1-5: VGPR_Count 68/96/144 proves
// the "register" arrays were actually re-fetched from L2/scratch each step).
__global__ __launch_bounds__(NTHREADS, 2)
void lstm_fused_kernel(const float* __restrict__ wave_input,   // [B, 360, 3]
                       const float* __restrict__ wave_future,  // [B, 1800, 3]
                       const float* __restrict__ W_ih,         // [256, 3]
                       const float* __restrict__ W_hh,         // [256, 64]
                       const float* __restrict__ b_ih,         // [256]
                       const float* __restrict__ b_hh,         // [256]
                       const float* __restrict__ W_proj,       // [64, 64]
                       const float* __restrict__ b_proj,       // [64]
                       float* __restrict__ out)                // [B, 50, 64]
{
    __shared__ __align__(16) float x_lds[T_TOT * IN_SZ];     // 24.7 KB
    __shared__ __align__(16) float wproj_lds[H_SZ * 65];     // 16.6 KB, padded
    __shared__ __align__(16) float gates_lds[2][NTHREADS];   // double-buffered

    const int b    = blockIdx.x;
    const int tid  = threadIdx.x;      // gate row index 0..255
    const int wv   = tid >> 6;
    const int lane = tid & 63;         // hidden unit this thread tracks

    // ---- stage x sequence (coalesced, one-time) ----
    {
        const float* wi = wave_input + (size_t)b * (T_PAST_ * IN_SZ);
        for (int i = tid; i < T_PAST_ * IN_SZ; i += NTHREADS) x_lds[i] = wi[i];
        const float* wf = wave_future + (size_t)b * (T_FUT_ * IN_SZ);
        for (int i = tid; i < MAX_STEPS * IN_SZ; i += NTHREADS)
            x_lds[T_PAST_ * IN_SZ + i] = wf[i];
    }
    // ---- W_proj rows, stride-65 pad (reads: 2 lanes/bank = free) ----
    for (int i = tid; i < H_SZ * H_SZ; i += NTHREADS) {
        int r = i >> 6, cc = i & 63;
        wproj_lds[r * 65 + cc] = W_proj[i];
    }

    // ---- W_hh row `tid`: 64 floats, loaded once, PINNED into VGPRs ----
    float w[H_SZ];
    {
        const float4* rowp = (const float4*)(W_hh + (size_t)tid * H_SZ);
        #pragma unroll
        for (int q = 0; q < 16; ++q) {
            float4 v = rowp[q];
            w[4 * q + 0] = v.x; w[4 * q + 1] = v.y;
            w[4 * q + 2] = v.z; w[4 * q + 3] = v.w;
        }
    }
    // asm pin: values become opaque asm outputs -> loads cannot be sunk into
    // the loop, values must stay live in VGPRs for the whole kernel.
    #pragma unroll
    for (int k = 0; k < H_SZ; k += 8)
        asm volatile("" : "+v"(w[k+0]), "+v"(w[k+1]), "+v"(w[k+2]), "+v"(w[k+3]),
                          "+v"(w[k+4]), "+v"(w[k+5]), "+v"(w[k+6]), "+v"(w[k+7]));

    const float wih0 = W_ih[tid * 3 + 0];
    const float wih1 = W_ih[tid * 3 + 1];
    const float wih2 = W_ih[tid * 3 + 2];
    const float bg   = b_ih[tid] + b_hh[tid];
    // unified activation: sigmoid for i,f,o; tanh(x)=2*sigmoid(2x)-1 for g
    const bool  isg = (tid >= 2 * H_SZ) && (tid < 3 * H_SZ);
    const float sc  = isg ? 2.0f : 1.0f;
    const float aa  = isg ? 2.0f : 1.0f;
    const float bb  = isg ? -1.0f : 0.0f;
    const float bpj = b_proj[lane];

    float h = 0.0f, c = 0.0f;          // unit `lane` state, per-wave copy
    float* outb = out + (size_t)b * (FUT_SEQ * H_SZ);
    int next_cp = T_PAST_ + WSPF_ - 1;
    int cp_k = 0;

    __syncthreads();

    for (int t = 0; t < T_TOT; ++t) {
        float x0 = x_lds[t * 3 + 0];   // uniform-address broadcast reads
        float x1 = x_lds[t * 3 + 1];
        float x2 = x_lds[t * 3 + 2];

        // 4 independent accumulator chains over k
        float a0 = fmaf(wih0, x0, bg);
        float a1 = fmaf(wih1, x1, 0.0f);
        float a2 = fmaf(wih2, x2, 0.0f);
        float a3 = 0.0f;
        #pragma unroll
        for (int k = 0; k < H_SZ; k += 4) {
            a0 = fmaf(w[k + 0], bcast_(h, k + 0), a0);
            a1 = fmaf(w[k + 1], bcast_(h, k + 1), a1);
            a2 = fmaf(w[k + 2], bcast_(h, k + 2), a2);
            a3 = fmaf(w[k + 3], bcast_(h, k + 3), a3);
        }
        float acc = (a0 + a1) + (a2 + a3);

        float e    = __expf(-sc * acc);
        float gval = fmaf(aa, rcp_(1.0f + e), bb);     // sigmoid / tanh
        gates_lds[t & 1][tid] = gval;
        __syncthreads();               // gates(t) visible to all waves

        // every wave redundantly updates unit `lane`
        float gi = gates_lds[t & 1][0 * H_SZ + lane];
        float gf = gates_lds[t & 1][1 * H_SZ + lane];
        float gg = gates_lds[t & 1][2 * H_SZ + lane];
        float go = gates_lds[t & 1][3 * H_SZ + lane];
        c = fmaf(gf, c, gi * gg);
        h = go * tanh_(c);
        // no 2nd barrier: double-buffered gates tolerate <=1-step wave skew

        if (t == next_cp) {            // block-uniform condition
            if (wv == 0) {             // lane = output unit j; h via readlane
                float p = bpj;
                #pragma unroll 8
                for (int m = 0; m < H_SZ; ++m)
                    p = fmaf(wproj_lds[lane * 65 + m], bcast_(h, m), p);
                outb[cp_k * H_SZ + lane] = p;
            }
            next_cp += WSPF_;
            ++cp_k;
        }
    }
}

extern "C" void kernel_launch(void* const* d_in, const int* in_sizes, int n_in,
                              void* d_out, int out_size, void* d_ws, size_t ws_size,
                              hipStream_t stream) {
    const float* wave_input  = (const float*)d_in[0];
    const float* wave_future = (const float*)d_in[1];
    const float* W_ih        = (const float*)d_in[2];
    const float* W_hh        = (const float*)d_in[3];
    const float* b_ih        = (const float*)d_in[4];
    const float* b_hh        = (const float*)d_in[5];
    const float* W_proj      = (const float*)d_in[6];
    const float* b_proj      = (const float*)d_in[7];
    float* out               = (float*)d_out;

    lstm_fused_kernel<<<BATCH, NTHREADS, 0, stream>>>(
        wave_input, wave_future, W_ih, W_hh, b_ih, b_hh, W_proj, b_proj, out);
}

// Round 8
// 1184.190 us; speedup vs baseline: 2.1740x; 1.0744x over previous
//
#include <hip/hip_runtime.h>
#include <math.h>

#define BATCH     512
#define T_PAST_   360
#define T_FUT_    1800
#define IN_SZ     3
#define H_SZ      64
#define FUT_SEQ   50
#define WSPF_     34
#define MAX_STEPS (FUT_SEQ * WSPF_)      // 1700
#define T_TOT     (T_PAST_ + MAX_STEPS)  // 2060
#define PSTRIDE   66                     // wproj row stride (2-way banks = free)

typedef __fp16 h2 __attribute__((ext_vector_type(2)));   // matches cvt_pkrtz/fdot2

__device__ __forceinline__ h2  as_h2(int v) { return __builtin_bit_cast(h2, v); }
__device__ __forceinline__ int as_i(h2 v)   { return __builtin_bit_cast(int, v); }

__device__ __forceinline__ float rcp_(float x) { return __builtin_amdgcn_rcpf(x); }

__device__ __forceinline__ float sigmoid_(float x) {
    return rcp_(1.0f + __expf(-x));
}

__device__ __forceinline__ float tanh_(float x) {
    float a = fabsf(x);
    float e = __expf(-2.0f * a);
    float t = (1.0f - e) * rcp_(1.0f + e);
    return copysignf(t, x);
}

// packed-pair dot with f32 accumulate: D = a.x*b.x + a.y*b.y + c
__device__ __forceinline__ float dot2_(int a, int b, float c) {
#if __has_builtin(__builtin_amdgcn_fdot2)
    return __builtin_amdgcn_fdot2(as_h2(a), as_h2(b), c, false);
#else
    h2 av = as_h2(a), bv = as_h2(b);
    return fmaf((float)av.x, (float)bv.x, fmaf((float)av.y, (float)bv.y, c));
#endif
}

// One wave per batch element; lane = hidden unit. Entire recurrence in
// registers: weights as packed half2 (4 gates x 32 pairs = 128 VGPRs), h
// broadcast by v_readlane of packed pairs, fdot2 does 2 MACs/issue with f32
// accumulate. State c/h and all activations stay fp32. No LDS access and no
// barrier anywhere in the 2060-step loop.
__global__ __launch_bounds__(64, 1)
void lstm_fused_kernel(const float* __restrict__ wave_input,   // [B, 360, 3]
                       const float* __restrict__ wave_future,  // [B, 1800, 3]
                       const float* __restrict__ W_ih,         // [256, 3]
                       const float* __restrict__ W_hh,         // [256, 64]
                       const float* __restrict__ b_ih,         // [256]
                       const float* __restrict__ b_hh,         // [256]
                       const float* __restrict__ W_proj,       // [64, 64]
                       const float* __restrict__ b_proj,       // [64]
                       float* __restrict__ out)                // [B, 50, 64]
{
    __shared__ __align__(16) float x_lds[T_TOT * IN_SZ];       // 24.7 KB
    __shared__ __align__(16) float wproj_lds[H_SZ * PSTRIDE];  // 16.9 KB

    const int b    = blockIdx.x;
    const int lane = threadIdx.x;      // hidden unit index

    // ---- stage x sequence (coalesced, one-time) ----
    {
        const float* wi = wave_input + (size_t)b * (T_PAST_ * IN_SZ);
        for (int i = lane; i < T_PAST_ * IN_SZ; i += 64) x_lds[i] = wi[i];
        const float* wf = wave_future + (size_t)b * (T_FUT_ * IN_SZ);
        for (int i = lane; i < MAX_STEPS * IN_SZ; i += 64)
            x_lds[T_PAST_ * IN_SZ + i] = wf[i];
    }
    for (int i = lane; i < H_SZ * H_SZ; i += 64) {
        int r = i >> 6, cc = i & 63;
        wproj_lds[r * PSTRIDE + cc] = W_proj[i];
    }

    // ---- 4 gate rows of W_hh for unit `lane`, packed fp16 pairs ----
    int wi2[32], wf2[32], wg2[32], wo2[32];
    {
        const float* pi = W_hh + (size_t)(0 * H_SZ + lane) * H_SZ;
        const float* pf = W_hh + (size_t)(1 * H_SZ + lane) * H_SZ;
        const float* pg = W_hh + (size_t)(2 * H_SZ + lane) * H_SZ;
        const float* po = W_hh + (size_t)(3 * H_SZ + lane) * H_SZ;
        #pragma unroll
        for (int j = 0; j < 32; ++j) {
            wi2[j] = as_i(__builtin_amdgcn_cvt_pkrtz(pi[2*j], pi[2*j+1]));
            wf2[j] = as_i(__builtin_amdgcn_cvt_pkrtz(pf[2*j], pf[2*j+1]));
            wg2[j] = as_i(__builtin_amdgcn_cvt_pkrtz(pg[2*j], pg[2*j+1]));
            wo2[j] = as_i(__builtin_amdgcn_cvt_pkrtz(po[2*j], po[2*j+1]));
        }
    }
    // pin packed weights as opaque VGPR values (loads can't sink into loop)
    #pragma unroll
    for (int k = 0; k < 32; k += 8) {
        asm volatile("" : "+v"(wi2[k+0]), "+v"(wi2[k+1]), "+v"(wi2[k+2]), "+v"(wi2[k+3]),
                          "+v"(wi2[k+4]), "+v"(wi2[k+5]), "+v"(wi2[k+6]), "+v"(wi2[k+7]));
        asm volatile("" : "+v"(wf2[k+0]), "+v"(wf2[k+1]), "+v"(wf2[k+2]), "+v"(wf2[k+3]),
                          "+v"(wf2[k+4]), "+v"(wf2[k+5]), "+v"(wf2[k+6]), "+v"(wf2[k+7]));
        asm volatile("" : "+v"(wg2[k+0]), "+v"(wg2[k+1]), "+v"(wg2[k+2]), "+v"(wg2[k+3]),
                          "+v"(wg2[k+4]), "+v"(wg2[k+5]), "+v"(wg2[k+6]), "+v"(wg2[k+7]));
        asm volatile("" : "+v"(wo2[k+0]), "+v"(wo2[k+1]), "+v"(wo2[k+2]), "+v"(wo2[k+3]),
                          "+v"(wo2[k+4]), "+v"(wo2[k+5]), "+v"(wo2[k+6]), "+v"(wo2[k+7]));
    }

    // per-gate W_ih rows (x-dim = 3) and combined biases, fp32
    const float wihi0 = W_ih[(0*H_SZ+lane)*3+0], wihi1 = W_ih[(0*H_SZ+lane)*3+1], wihi2 = W_ih[(0*H_SZ+lane)*3+2];
    const float wihf0 = W_ih[(1*H_SZ+lane)*3+0], wihf1 = W_ih[(1*H_SZ+lane)*3+1], wihf2 = W_ih[(1*H_SZ+lane)*3+2];
    const float wihg0 = W_ih[(2*H_SZ+lane)*3+0], wihg1 = W_ih[(2*H_SZ+lane)*3+1], wihg2 = W_ih[(2*H_SZ+lane)*3+2];
    const float wiho0 = W_ih[(3*H_SZ+lane)*3+0], wiho1 = W_ih[(3*H_SZ+lane)*3+1], wiho2 = W_ih[(3*H_SZ+lane)*3+2];
    const float bi = b_ih[0*H_SZ+lane] + b_hh[0*H_SZ+lane];
    const float bf = b_ih[1*H_SZ+lane] + b_hh[1*H_SZ+lane];
    const float bg = b_ih[2*H_SZ+lane] + b_hh[2*H_SZ+lane];
    const float bo = b_ih[3*H_SZ+lane] + b_hh[3*H_SZ+lane];
    const float bpj = b_proj[lane];

    float h = 0.0f, c = 0.0f;          // unit `lane` state, fp32
    int   pk = 0;                      // packed (h_2j, h_2j+1) on even lanes
    float* outb = out + (size_t)b * (FUT_SEQ * H_SZ);
    int next_cp = T_PAST_ + WSPF_ - 1;
    int cp_k = 0;

    __syncthreads();                    // staging visible

    for (int t = 0; t < T_TOT; ++t) {
        float x0 = x_lds[t * 3 + 0];   // uniform-address broadcast reads
        float x1 = x_lds[t * 3 + 1];
        float x2 = x_lds[t * 3 + 2];

        float ai = fmaf(wihi0, x0, fmaf(wihi1, x1, fmaf(wihi2, x2, bi)));
        float af = fmaf(wihf0, x0, fmaf(wihf1, x1, fmaf(wihf2, x2, bf)));
        float ag = fmaf(wihg0, x0, fmaf(wihg1, x1, fmaf(wihg2, x2, bg)));
        float ao = fmaf(wiho0, x0, fmaf(wiho1, x1, fmaf(wiho2, x2, bo)));

        // ---- W_hh @ h : packed pairs broadcast from even lanes ----
        #pragma unroll
        for (int j = 0; j < 32; ++j) {
            int hp = __builtin_amdgcn_readlane(pk, 2 * j);
            ai = dot2_(wi2[j], hp, ai);
            af = dot2_(wf2[j], hp, af);
            ag = dot2_(wg2[j], hp, ag);
            ao = dot2_(wo2[j], hp, ao);
        }

        // ---- activations + state update, fp32 in-lane ----
        float gi = sigmoid_(ai);
        float gf = sigmoid_(af);
        float gg = tanh_(ag);
        float go = sigmoid_(ao);
        c = fmaf(gf, c, gi * gg);
        h = go * tanh_(c);

        // repack h for next step: even lane 2j -> (h_2j, h_2j+1)
        float hn = __shfl_xor(h, 1, 64);
        pk = as_i(__builtin_amdgcn_cvt_pkrtz(h, hn));

        if (t == next_cp) {            // wave-uniform
            float p = bpj;
            #pragma unroll
            for (int j = 0; j < 32; ++j) {
                h2 hp = as_h2(__builtin_amdgcn_readlane(pk, 2 * j));
                p = fmaf(wproj_lds[lane * PSTRIDE + 2*j    ], (float)hp.x, p);
                p = fmaf(wproj_lds[lane * PSTRIDE + 2*j + 1], (float)hp.y, p);
            }
            outb[cp_k * H_SZ + lane] = p;
            next_cp += WSPF_;
            ++cp_k;
        }
    }
}

extern "C" void kernel_launch(void* const* d_in, const int* in_sizes, int n_in,
                              void* d_out, int out_size, void* d_ws, size_t ws_size,
                              hipStream_t stream) {
    const float* wave_input  = (const float*)d_in[0];
    const float* wave_future = (const float*)d_in[1];
    const float* W_ih        = (const float*)d_in[2];
    const float* W_hh        = (const float*)d_in[3];
    const float* b_ih        = (const float*)d_in[4];
    const float* b_hh        = (const float*)d_in[5];
    const float* W_proj      = (const float*)d_in[6];
    const float* b_proj      = (const float*)d_in[7];
    float* out               = (float*)d_out;

    lstm_fused_kernel<<<BATCH, 64, 0, stream>>>(
        wave_input, wave_future, W_ih, W_hh, b_ih, b_hh, W_proj, b_proj, out);
}

// Round 9
// 967.664 us; speedup vs baseline: 2.6605x; 1.2238x over previous
//
#include <hip/hip_runtime.h>
#include <math.h>

#define BATCH     512
#define T_PAST_   360
#define T_FUT_    1800
#define IN_SZ     3
#define H_SZ      64
#define FUT_SEQ   50
#define WSPF_     34
#define MAX_STEPS (FUT_SEQ * WSPF_)      // 1700
#define T_TOT     (T_PAST_ + MAX_STEPS)  // 2060
#define NTHREADS  256
#define PSTRIDE   66                     // wproj row stride (2-way banks = free)

typedef __fp16 h2 __attribute__((ext_vector_type(2)));

__device__ __forceinline__ h2  as_h2(int v) { return __builtin_bit_cast(h2, v); }
__device__ __forceinline__ int as_i(h2 v)   { return __builtin_bit_cast(int, v); }

__device__ __forceinline__ float rcp_(float x) { return __builtin_amdgcn_rcpf(x); }

__device__ __forceinline__ float tanh_(float x) {
    float a = fabsf(x);
    float e = __expf(-2.0f * a);         // in (0,1], no overflow
    float t = (1.0f - e) * rcp_(1.0f + e);
    return copysignf(t, x);
}

// packed-pair dot with f32 accumulate: D = a.x*b.x + a.y*b.y + c
__device__ __forceinline__ float dot2_(int a, int b, float c) {
#if __has_builtin(__builtin_amdgcn_fdot2)
    return __builtin_amdgcn_fdot2(as_h2(a), as_h2(b), c, false);
#else
    h2 av = as_h2(a), bv = as_h2(b);
    return fmaf((float)av.x, (float)bv.x, fmaf((float)av.y, (float)bv.y, c));
#endif
}

// 256 threads / 4 waves per batch element; thread = gate row (32 packed-fp16
// weight VGPRs -> no AGPR/spill pressure, the killer of rounds 1-8). h is
// exchanged as packed half2 pairs through per-wave private LDS buffers
// (uniform-address ds_read_b128 broadcast, 8 reads/step), gates through one
// double-buffered block barrier per step. 2 blocks/CU = 2 waves/SIMD so FMA /
// transcendental / LDS latency overlaps across waves (round 8 had 1 wave/SIMD
// and stalled 70% of every step).
__global__ __launch_bounds__(NTHREADS, 2)
void lstm_fused_kernel(const float* __restrict__ wave_input,   // [B, 360, 3]
                       const float* __restrict__ wave_future,  // [B, 1800, 3]
                       const float* __restrict__ W_ih,         // [256, 3]
                       const float* __restrict__ W_hh,         // [256, 64]
                       const float* __restrict__ b_ih,         // [256]
                       const float* __restrict__ b_hh,         // [256]
                       const float* __restrict__ W_proj,       // [64, 64]
                       const float* __restrict__ b_proj,       // [64]
                       float* __restrict__ out)                // [B, 50, 64]
{
    __shared__ __align__(16) float x_lds[T_TOT * IN_SZ];       // 24.7 KB
    __shared__ __align__(16) float wproj_lds[H_SZ * PSTRIDE];  // 16.9 KB
    __shared__ __align__(16) float gates_lds[2][NTHREADS];     // 2 KB
    __shared__ __align__(16) int   h2_lds[4][2][H_SZ / 2];     // per-wave, 1 KB

    const int b    = blockIdx.x;
    const int tid  = threadIdx.x;      // gate row 0..255
    const int wv   = tid >> 6;
    const int lane = tid & 63;         // hidden unit this thread updates

    // ---- stage x sequence (coalesced, one-time) ----
    {
        const float* wi = wave_input + (size_t)b * (T_PAST_ * IN_SZ);
        for (int i = tid; i < T_PAST_ * IN_SZ; i += NTHREADS) x_lds[i] = wi[i];
        const float* wf = wave_future + (size_t)b * (T_FUT_ * IN_SZ);
        for (int i = tid; i < MAX_STEPS * IN_SZ; i += NTHREADS)
            x_lds[T_PAST_ * IN_SZ + i] = wf[i];
    }
    for (int i = tid; i < H_SZ * H_SZ; i += NTHREADS) {
        int r = i >> 6, cc = i & 63;
        wproj_lds[r * PSTRIDE + cc] = W_proj[i];
    }
    if (lane < 32) h2_lds[wv][0][lane] = 0;    // h=0 for step 0 read

    // ---- W_hh row `tid` as 32 packed fp16 pairs (32 VGPRs) ----
    int w2[32];
    {
        const float* rowp = W_hh + (size_t)tid * H_SZ;
        #pragma unroll
        for (int j = 0; j < 32; ++j)
            w2[j] = as_i(__builtin_amdgcn_cvt_pkrtz(rowp[2*j], rowp[2*j+1]));
    }
    #pragma unroll
    for (int k = 0; k < 32; k += 8)
        asm volatile("" : "+v"(w2[k+0]), "+v"(w2[k+1]), "+v"(w2[k+2]), "+v"(w2[k+3]),
                          "+v"(w2[k+4]), "+v"(w2[k+5]), "+v"(w2[k+6]), "+v"(w2[k+7]));

    const float wih0 = W_ih[tid * 3 + 0];
    const float wih1 = W_ih[tid * 3 + 1];
    const float wih2 = W_ih[tid * 3 + 2];
    const float bg   = b_ih[tid] + b_hh[tid];
    // unified activation: sigmoid for i,f,o; tanh(x) = 2*sigmoid(2x)-1 for g
    const bool  isg = (tid >= 2 * H_SZ) && (tid < 3 * H_SZ);
    const float sc  = isg ? 2.0f : 1.0f;
    const float aa  = isg ? 2.0f : 1.0f;
    const float bb  = isg ? -1.0f : 0.0f;
    const float bpj = b_proj[lane];

    float c = 0.0f;                    // unit `lane` state, per-wave copy
    float* outb = out + (size_t)b * (FUT_SEQ * H_SZ);
    int next_cp = T_PAST_ + WSPF_ - 1;
    int cp_k = 0;

    __syncthreads();

    for (int t = 0; t < T_TOT; ++t) {
        float x0 = x_lds[t * 3 + 0];   // uniform-address broadcast reads
        float x1 = x_lds[t * 3 + 1];
        float x2 = x_lds[t * 3 + 2];

        // ---- dot: 8 uniform b128 reads of own wave's packed h, 32 fdot2 ----
        const int4* hp4 = (const int4*)h2_lds[wv][t & 1];
        float a0 = fmaf(wih0, x0, bg);
        float a1 = fmaf(wih1, x1, 0.0f);
        float a2 = fmaf(wih2, x2, 0.0f);
        float a3 = 0.0f;
        #pragma unroll
        for (int q = 0; q < 8; ++q) {
            int4 pv = hp4[q];
            a0 = dot2_(w2[4*q+0], pv.x, a0);
            a1 = dot2_(w2[4*q+1], pv.y, a1);
            a2 = dot2_(w2[4*q+2], pv.z, a2);
            a3 = dot2_(w2[4*q+3], pv.w, a3);
        }
        float acc = (a0 + a1) + (a2 + a3);

        float e    = __expf(-sc * acc);
        float gval = fmaf(aa, rcp_(1.0f + e), bb);     // sigmoid / tanh
        gates_lds[t & 1][tid] = gval;
        __syncthreads();               // gates(t) visible to all waves

        // ---- update (all waves redundantly, unit `lane`) ----
        float gi = gates_lds[t & 1][0 * H_SZ + lane];
        float gf = gates_lds[t & 1][1 * H_SZ + lane];
        float gg = gates_lds[t & 1][2 * H_SZ + lane];
        float go = gates_lds[t & 1][3 * H_SZ + lane];
        c = fmaf(gf, c, gi * gg);
        float h = go * tanh_(c);

        // pack (h_2j, h_2j+1) on even lanes, write own wave's next-buf copy
        float hn = __shfl_xor(h, 1, 64);
        int pk = as_i(__builtin_amdgcn_cvt_pkrtz(h, hn));
        if ((lane & 1) == 0) h2_lds[wv][(t + 1) & 1][lane >> 1] = pk;
        // no 2nd barrier: per-wave buffer, in-wave ordering via lgkmcnt;
        // gates double-buffer tolerates <=1-step wave skew

        if (t == next_cp) {            // block-uniform condition
            if (wv == 0) {             // pk holds valid pairs on even lanes
                float p = bpj;
                #pragma unroll
                for (int j = 0; j < 32; ++j) {
                    h2 hp = as_h2(__builtin_amdgcn_readlane(pk, 2 * j));
                    p = fmaf(wproj_lds[lane * PSTRIDE + 2*j    ], (float)hp.x, p);
                    p = fmaf(wproj_lds[lane * PSTRIDE + 2*j + 1], (float)hp.y, p);
                }
                outb[cp_k * H_SZ + lane] = p;
            }
            next_cp += WSPF_;
            ++cp_k;
        }
    }
}

extern "C" void kernel_launch(void* const* d_in, const int* in_sizes, int n_in,
                              void* d_out, int out_size, void* d_ws, size_t ws_size,
                              hipStream_t stream) {
    const float* wave_input  = (const float*)d_in[0];
    const float* wave_future = (const float*)d_in[1];
    const float* W_ih        = (const float*)d_in[2];
    const float* W_hh        = (const float*)d_in[3];
    const float* b_ih        = (const float*)d_in[4];
    const float* b_hh        = (const float*)d_in[5];
    const float* W_proj      = (const float*)d_in[6];
    const float* b_proj      = (const float*)d_in[7];
    float* out               = (float*)d_out;

    lstm_fused_kernel<<<BATCH, NTHREADS, 0, stream>>>(
        wave_input, wave_future, W_ih, W_hh, b_ih, b_hh, W_proj, b_proj, out);
}